// Round 9
// baseline (341.223 us; speedup 1.0000x reference)
//
#include <hip/hip_runtime.h>

// ---------------------------------------------------------------------------
// 2-layer GCN forward (PyG GCNConv, add_self_loops, sym-norm), CSR-gather.
//   dinv = rsqrt(segsum(ew,dst)+1)
//   h    = relu( Agg(norm, x@W1) + dinv^2*(x@W1) + b1 )
//   out  = L2norm( Agg(norm, h@W2) + dinv^2*(h@W2) + b2 )
// GEMM1: bf16 MFMA; W1 hi+lo split, x single bf16. xw1 bf16. hw2 bf16 pad-48.
// FAT kernel: gemm1 + deg_hist co-scheduled; deg uses 8 XCD-local histogram
// replicas (blockIdx&7) to kill cross-XCD atomic line ping-pong.
// k_gg: gather1 + gemm2 fused (no agg1 round-trip).
// ---------------------------------------------------------------------------

typedef unsigned short u16;
typedef unsigned long long u64;
typedef __attribute__((ext_vector_type(8))) short short8;
typedef __attribute__((ext_vector_type(4))) float f32x4;

#define FIXSCALE 4194304.0f   // 2^22
#define HW2S 48               // hw2 row stride (bf16), 40 real + 8 pad

static __device__ inline u16 f2bf(float f) {            // RNE f32 -> bf16 bits
    unsigned u = __float_as_uint(f);
    return (u16)((u + 0x7fffu + ((u >> 16) & 1u)) >> 16);
}
static __device__ inline float bf2f(u16 h) { return __uint_as_float(((unsigned)h) << 16); }

// ---- FAT kernel: [0, gB) = gemm1 tiles, [gB, gB+dB) = deg_hist chunks ------
__launch_bounds__(256)
__global__ void k_fat1(const float* __restrict__ x, const u16* __restrict__ wt_hi,
                       const u16* __restrict__ wt_lo, u16* __restrict__ xw1, int N,
                       const int* __restrict__ dst, const float* __restrict__ ew,
                       u64* __restrict__ hist, int* __restrict__ rank, int E, int gB) {
    __shared__ __align__(16) u16 Ah[128 * 40];
    __shared__ __align__(16) u16 Bh[128 * 40];
    __shared__ __align__(16) u16 Bl[128 * 40];

    if (blockIdx.x >= gB) {
        // -------- deg_hist with XCD-local replica (atomic-latency bound) ----
        int bi = blockIdx.x - gB;
        int i = bi * 256 + threadIdx.x;
        if (i < E) {
            int rep = bi & 7;
            int d = dst[i];
            u64 v = (1ULL << 32) |
                (u64)(unsigned)__float2uint_rn(ew[i] * FIXSCALE);
            u64 old = atomicAdd(&hist[(size_t)rep * N + d], v);
            rank[i] = ((int)(old >> 32)) | (rep << 16);
        }
        return;
    }

    // ---------------- gemm1 part (MFMA) ----------------
    const int t = threadIdx.x;
    const int w = t >> 6;
    const int lane = t & 63;
    const int lrow = lane & 15;
    const int lk = (lane >> 4) * 8;
    const int row0 = blockIdx.x * 128;

    f32x4 acc[2][8] = {};

    for (int kt = 0; kt < 8; ++kt) {
#pragma unroll
        for (int i = 0; i < 4; ++i) {
            int flat = t + i * 256;
            int r = flat >> 3, c4 = flat & 7;
            int gr = row0 + r;
            float4 v = make_float4(0.f, 0.f, 0.f, 0.f);
            if (gr < N) v = *(const float4*)(x + (size_t)gr * 256 + kt * 32 + c4 * 4);
            ushort4 vh;
            vh.x = f2bf(v.x);
            vh.y = f2bf(v.y);
            vh.z = f2bf(v.z);
            vh.w = f2bf(v.w);
            *(ushort4*)(Ah + r * 40 + c4 * 4) = vh;
        }
#pragma unroll
        for (int i = 0; i < 2; ++i) {
            int flat = t + i * 256;
            int n = flat >> 2, c = flat & 3;
            *(short8*)(Bh + n * 40 + c * 8) =
                *(const short8*)(wt_hi + (size_t)n * 256 + kt * 32 + c * 8);
            *(short8*)(Bl + n * 40 + c * 8) =
                *(const short8*)(wt_lo + (size_t)n * 256 + kt * 32 + c * 8);
        }
        __syncthreads();

        short8 a0 = *(const short8*)(Ah + (w * 32 + lrow) * 40 + lk);
        short8 a1 = *(const short8*)(Ah + (w * 32 + 16 + lrow) * 40 + lk);
#pragma unroll
        for (int ni = 0; ni < 8; ++ni) {
            short8 bh = *(const short8*)(Bh + (ni * 16 + lrow) * 40 + lk);
            short8 bl = *(const short8*)(Bl + (ni * 16 + lrow) * 40 + lk);
            acc[0][ni] = __builtin_amdgcn_mfma_f32_16x16x32_bf16(a0, bh, acc[0][ni], 0, 0, 0);
            acc[1][ni] = __builtin_amdgcn_mfma_f32_16x16x32_bf16(a1, bh, acc[1][ni], 0, 0, 0);
            acc[0][ni] = __builtin_amdgcn_mfma_f32_16x16x32_bf16(a0, bl, acc[0][ni], 0, 0, 0);
            acc[1][ni] = __builtin_amdgcn_mfma_f32_16x16x32_bf16(a1, bl, acc[1][ni], 0, 0, 0);
        }
        __syncthreads();
    }

#pragma unroll
    for (int mi = 0; mi < 2; ++mi) {
        int rbase = row0 + w * 32 + mi * 16 + (lane >> 4) * 4;
#pragma unroll
        for (int r = 0; r < 4; ++r) {
            int gr = rbase + r;
            if (gr < N) {
                u16* p = xw1 + (size_t)gr * 128 + (lane & 15);
#pragma unroll
                for (int ni = 0; ni < 8; ++ni) p[ni * 16] = f2bf(acc[mi][ni][r]);
            }
        }
    }
}

// dinv from summed replicas; per-block count totals
__launch_bounds__(256)
__global__ void k_prep(const u64* __restrict__ hist,
                       float* __restrict__ dinv, int* __restrict__ blkTot, int N) {
    __shared__ int red[256];
    int t = threadIdx.x;
    int i = blockIdx.x * 256 + t;
    int cnt = 0;
    if (i < N) {
        u64 degfix = 0;
#pragma unroll
        for (int r = 0; r < 8; ++r) {
            u64 p = hist[(size_t)r * N + i];
            cnt += (int)(p >> 32);
            degfix += (p & 0xffffffffULL);
        }
        dinv[i] = rsqrtf((float)degfix * (1.0f / FIXSCALE) + 1.0f);
    }
    red[t] = cnt;
    __syncthreads();
#pragma unroll
    for (int off = 128; off > 0; off >>= 1) {
        if (t < off) red[t] += red[t + off];
        __syncthreads();
    }
    if (t == 0) blkTot[blockIdx.x] = red[0];
}

__launch_bounds__(512)
__global__ void k_scanblk(const int* __restrict__ blkTot, int* __restrict__ blkOff,
                          int* __restrict__ rowp, int NB, int N, int E) {
    __shared__ int s[512];
    int t = threadIdx.x;
    int v = (t < NB) ? blkTot[t] : 0;
    s[t] = v;
    __syncthreads();
    for (int off = 1; off < 512; off <<= 1) {
        int u = (t >= off) ? s[t - off] : 0;
        __syncthreads();
        s[t] += u;
        __syncthreads();
    }
    if (t < NB) blkOff[t] = s[t] - v;
    if (t == 0) rowp[N] = E;
}

// rowp + per-(node,replica) absolute base offsets
__launch_bounds__(256)
__global__ void k_rowp(const u64* __restrict__ hist, const int* __restrict__ blkOff,
                       int* __restrict__ rowp, int* __restrict__ base, int N) {
    __shared__ int s[256];
    int t = threadIdx.x;
    int i = blockIdx.x * 256 + t;
    int c[8];
    int cnt = 0;
    if (i < N) {
#pragma unroll
        for (int r = 0; r < 8; ++r) {
            c[r] = (int)(hist[(size_t)r * N + i] >> 32);
            cnt += c[r];
        }
    }
    s[t] = cnt;
    __syncthreads();
    for (int off = 1; off < 256; off <<= 1) {
        int u = (t >= off) ? s[t - off] : 0;
        __syncthreads();
        s[t] += u;
        __syncthreads();
    }
    if (i < N) {
        int run = blkOff[blockIdx.x] + s[t] - cnt;
        rowp[i] = run;
#pragma unroll
        for (int r = 0; r < 8; ++r) {
            base[(size_t)i * 8 + r] = run;
            run += c[r];
        }
    }
}

__global__ void k_fill(const int* __restrict__ src, const int* __restrict__ dst,
                       const float* __restrict__ ew, const int* __restrict__ rank,
                       const float* __restrict__ dinv, const int* __restrict__ base,
                       int2* __restrict__ entries, int E) {
    int e = blockIdx.x * 256 + threadIdx.x;
    if (e < E) {
        int s = src[e], d = dst[e];
        float w = dinv[s] * ew[e] * dinv[d];
        int rk = rank[e];
        int slot = base[(size_t)d * 8 + (rk >> 16)] + (rk & 0xffff);
        entries[slot] = make_int2(s, __float_as_int(w));
    }
}

// W1[256,128] f32 -> Wt_hi/Wt_lo[128,256] bf16 (transposed, split precision)
__global__ void k_wsplit(const float* __restrict__ W1, u16* __restrict__ wt_hi,
                         u16* __restrict__ wt_lo) {
    int idx = blockIdx.x * 256 + threadIdx.x;
    if (idx < 256 * 128) {
        int n = idx & 127, k = idx >> 7;
        float f = W1[idx];
        u16 h = f2bf(f);
        wt_hi[n * 256 + k] = h;
        wt_lo[n * 256 + k] = f2bf(f - bf2f(h));
    }
}

// Fused gather1 + gemm2: per block of 8 nodes,
//   h[n] = relu(dinv^2*xw1[n] + sum_e w_e*xw1[src_e] + b1)  -> LDS
//   hw2[n] = h[n] @ W2  (bf16, stride 48, cols 40-47 zero)
__launch_bounds__(256)
__global__ void k_gg(const u16* __restrict__ xw1, const int2* __restrict__ entries,
                     const int* __restrict__ row, const float* __restrict__ dinv,
                     const float* __restrict__ b1, const float* __restrict__ W2,
                     u16* __restrict__ hw2, int N) {
    __shared__ float hrow[8 * 128];
    __shared__ float w2s[128 * 40];
    const int t = threadIdx.x;

    // stage W2 (20KB, L2-resident broadcast)
    for (int idx = t; idx < 1280; idx += 256)
        ((float4*)w2s)[idx] = ((const float4*)W2)[idx];

    int g = blockIdx.x * 8 + (t >> 5);
    int j = (t & 31) * 4;
    if (g < N) {
        float di = dinv[g];
        float d2 = di * di;
        ushort4 sv = *(const ushort4*)(xw1 + (size_t)g * 128 + j);
        float4 acc = make_float4(d2 * bf2f(sv.x), d2 * bf2f(sv.y),
                                 d2 * bf2f(sv.z), d2 * bf2f(sv.w));
        int e = row[g], end = row[g + 1];
        for (; e + 2 <= end; e += 2) {
            int2 e0 = entries[e];
            int2 e1 = entries[e + 1];
            ushort4 v0 = *(const ushort4*)(xw1 + (size_t)e0.x * 128 + j);
            ushort4 v1 = *(const ushort4*)(xw1 + (size_t)e1.x * 128 + j);
            float w0 = __int_as_float(e0.y), w1 = __int_as_float(e1.y);
            acc.x += w0 * bf2f(v0.x) + w1 * bf2f(v1.x);
            acc.y += w0 * bf2f(v0.y) + w1 * bf2f(v1.y);
            acc.z += w0 * bf2f(v0.z) + w1 * bf2f(v1.z);
            acc.w += w0 * bf2f(v0.w) + w1 * bf2f(v1.w);
        }
        if (e < end) {
            int2 e0 = entries[e];
            ushort4 v0 = *(const ushort4*)(xw1 + (size_t)e0.x * 128 + j);
            float w0 = __int_as_float(e0.y);
            acc.x += w0 * bf2f(v0.x);
            acc.y += w0 * bf2f(v0.y);
            acc.z += w0 * bf2f(v0.z);
            acc.w += w0 * bf2f(v0.w);
        }
        float4 bb = *(const float4*)(b1 + j);
        float* hp = hrow + (t >> 5) * 128 + j;
        hp[0] = fmaxf(acc.x + bb.x, 0.f);
        hp[1] = fmaxf(acc.y + bb.y, 0.f);
        hp[2] = fmaxf(acc.z + bb.z, 0.f);
        hp[3] = fmaxf(acc.w + bb.w, 0.f);
    }
    __syncthreads();

    // mini-GEMM: 8 nodes x 48 cols (cols >= 40 are zero pad)
    for (int o = t; o < 8 * 48; o += 256) {
        int node = o / 48, col = o - node * 48;
        int gn = blockIdx.x * 8 + node;
        if (gn >= N) continue;
        float s = 0.f;
        if (col < 40) {
            const float* hr = hrow + node * 128;
#pragma unroll 4
            for (int k = 0; k < 128; ++k) s += hr[k] * w2s[k * 40 + col];
        }
        hw2[(size_t)gn * HW2S + col] = f2bf(s);
    }
}

// gather layer 2 + bias + fused L2 normalize -> out
__launch_bounds__(256)
__global__ void k_gather2(const u16* __restrict__ hw2, const int2* __restrict__ entries,
                          const int* __restrict__ row, const float* __restrict__ dinv,
                          const float* __restrict__ b2, float* __restrict__ out, int N) {
    int g = (blockIdx.x * 256 + threadIdx.x) >> 3;
    if (g >= N) return;
    int l = threadIdx.x & 7;
    int c0 = l * 6;
    float di = dinv[g];
    float d2 = di * di;
    float bb[6];
#pragma unroll
    for (int k = 0; k < 6; ++k) bb[k] = (c0 + k < 40) ? b2[c0 + k] : 0.f;

    float acc[6];
    {
        const u16* hn = hw2 + (size_t)g * HW2S + c0;
        ushort2 s0 = *(const ushort2*)(hn);
        ushort2 s1 = *(const ushort2*)(hn + 2);
        ushort2 s2 = *(const ushort2*)(hn + 4);
        acc[0] = d2 * bf2f(s0.x) + bb[0];
        acc[1] = d2 * bf2f(s0.y) + bb[1];
        acc[2] = d2 * bf2f(s1.x) + bb[2];
        acc[3] = d2 * bf2f(s1.y) + bb[3];
        acc[4] = d2 * bf2f(s2.x) + bb[4];
        acc[5] = d2 * bf2f(s2.y) + bb[5];
    }
    int e = row[g], end = row[g + 1];
    for (; e < end; ++e) {
        int2 ent = entries[e];
        float w = __int_as_float(ent.y);
        const u16* hr = hw2 + (size_t)ent.x * HW2S + c0;
        ushort2 v0 = *(const ushort2*)(hr);
        ushort2 v1 = *(const ushort2*)(hr + 2);
        ushort2 v2 = *(const ushort2*)(hr + 4);
        acc[0] += w * bf2f(v0.x);
        acc[1] += w * bf2f(v0.y);
        acc[2] += w * bf2f(v1.x);
        acc[3] += w * bf2f(v1.y);
        acc[4] += w * bf2f(v2.x);
        acc[5] += w * bf2f(v2.y);
    }
    float ss = 0.f;
#pragma unroll
    for (int k = 0; k < 6; ++k) ss += acc[k] * acc[k];
    ss += __shfl_xor(ss, 1);
    ss += __shfl_xor(ss, 2);
    ss += __shfl_xor(ss, 4);
    float inv = 1.f / fmaxf(sqrtf(ss), 1e-12f);
#pragma unroll
    for (int k = 0; k < 6; ++k) {
        int c = c0 + k;
        if (c < 40) out[(size_t)g * 40 + c] = acc[k] * inv;
    }
}

extern "C" void kernel_launch(void* const* d_in, const int* in_sizes, int n_in,
                              void* d_out, int out_size, void* d_ws, size_t ws_size,
                              hipStream_t stream) {
    const float* x   = (const float*)d_in[0];
    const int*   ei  = (const int*)d_in[1];
    const float* ew  = (const float*)d_in[2];
    const float* W1  = (const float*)d_in[3];
    const float* b1  = (const float*)d_in[4];
    const float* W2  = (const float*)d_in[5];
    const float* b2  = (const float*)d_in[6];
    float* out = (float*)d_out;

    const int N = in_sizes[0] / 256;   // 100000
    const int E = in_sizes[2];         // 1600000
    const int* src = ei;
    const int* dst = ei + E;
    const int NB = (N + 255) / 256;

    char* ws = (char*)d_ws;
    size_t off = 0;
    auto take = [&](size_t bytes) -> void* {
        void* p = (void*)(ws + off);
        off += (bytes + 255) & ~(size_t)255;
        return p;
    };
    u64*   hist    = (u64*)take((size_t)8 * N * 8);        // 8 XCD-local replicas
    int*   rank    = (int*)take((size_t)E * 4);
    float* dinv    = (float*)take((size_t)N * 4);
    int*   blkTot  = (int*)take((size_t)NB * 4);
    int*   blkOff  = (int*)take((size_t)NB * 4);
    int*   rowp    = (int*)take((size_t)(N + 1) * 4);
    int*   base    = (int*)take((size_t)N * 8 * 4);        // per (node, replica)
    int2*  entries = (int2*)take((size_t)E * 8);
    u16*   wt_hi   = (u16*)take((size_t)128 * 256 * 2);
    u16*   wt_lo   = (u16*)take((size_t)128 * 256 * 2);
    u16*   xw1     = (u16*)take((size_t)N * 128 * 2);
    u16*   hw2     = (u16*)take((size_t)N * HW2S * 2);

    hipMemsetAsync(hist, 0, (size_t)8 * N * 8, stream);
    k_wsplit<<<(256 * 128 + 255) / 256, 256, 0, stream>>>(W1, wt_hi, wt_lo);

    const int gB = (N + 127) / 128;           // 782 gemm tiles
    const int dB = (E + 255) / 256;           // 6250 deg chunks
    k_fat1<<<gB + dB, 256, 0, stream>>>(x, wt_hi, wt_lo, xw1, N,
                                        dst, ew, hist, rank, E, gB);

    k_prep<<<NB, 256, 0, stream>>>(hist, dinv, blkTot, N);
    k_scanblk<<<1, 512, 0, stream>>>(blkTot, blkOff, rowp, NB, N, E);
    k_rowp<<<NB, 256, 0, stream>>>(hist, blkOff, rowp, base, N);
    k_fill<<<(E + 255) / 256, 256, 0, stream>>>(src, dst, ew, rank, dinv, base, entries, E);

    k_gg<<<(N + 7) / 8, 256, 0, stream>>>(xw1, entries, rowp, dinv, b1, W2, hw2, N);
    k_gather2<<<(N * 8 + 255) / 256, 256, 0, stream>>>(hw2, entries, rowp, dinv, b2, out, N);
}

// Round 10
// 324.660 us; speedup vs baseline: 1.0510x; 1.0510x over previous
//
#include <hip/hip_runtime.h>

// ---------------------------------------------------------------------------
// 2-layer GCN forward (PyG GCNConv, add_self_loops, sym-norm), CSR-gather.
//   dinv = rsqrt(segsum(ew,dst)+1)
//   h    = relu( Agg(norm, x@W1) + dinv^2*(x@W1) + b1 )
//   out  = L2norm( Agg(norm, h@W2) + dinv^2*(h@W2) + b2 )
// GEMM1: bf16 MFMA; W1 hi+lo split, x single bf16. xw1 bf16. hw2 bf16 pad-48.
// FAT kernel: gemm1 + deg_hist co-scheduled; deg uses 8 XCD-local histogram
// replicas (blockIdx&7). gather1/gemm2 SEPARATE (R8 fusion regressed: LDS
// bank conflicts + VALU cost > the 51MB round-trip it saved).
// ---------------------------------------------------------------------------

typedef unsigned short u16;
typedef unsigned long long u64;
typedef __attribute__((ext_vector_type(8))) short short8;
typedef __attribute__((ext_vector_type(4))) float f32x4;

#define FIXSCALE 4194304.0f   // 2^22
#define HW2S 48               // hw2 row stride (bf16), 40 real + 8 pad

static __device__ inline u16 f2bf(float f) {            // RNE f32 -> bf16 bits
    unsigned u = __float_as_uint(f);
    return (u16)((u + 0x7fffu + ((u >> 16) & 1u)) >> 16);
}
static __device__ inline float bf2f(u16 h) { return __uint_as_float(((unsigned)h) << 16); }

// ---- FAT kernel: [0, gB) = gemm1 tiles, [gB, gB+dB) = deg_hist chunks ------
__launch_bounds__(256)
__global__ void k_fat1(const float* __restrict__ x, const u16* __restrict__ wt_hi,
                       const u16* __restrict__ wt_lo, u16* __restrict__ xw1, int N,
                       const int* __restrict__ dst, const float* __restrict__ ew,
                       u64* __restrict__ hist, int* __restrict__ rank, int E, int gB) {
    __shared__ __align__(16) u16 Ah[128 * 40];
    __shared__ __align__(16) u16 Bh[128 * 40];
    __shared__ __align__(16) u16 Bl[128 * 40];

    if (blockIdx.x >= gB) {
        // -------- deg_hist with XCD-local replica (atomic-latency bound) ----
        int bi = blockIdx.x - gB;
        int i = bi * 256 + threadIdx.x;
        if (i < E) {
            int rep = bi & 7;
            int d = dst[i];
            u64 v = (1ULL << 32) |
                (u64)(unsigned)__float2uint_rn(ew[i] * FIXSCALE);
            u64 old = atomicAdd(&hist[(size_t)rep * N + d], v);
            rank[i] = ((int)(old >> 32)) | (rep << 16);
        }
        return;
    }

    // ---------------- gemm1 part (MFMA) ----------------
    const int t = threadIdx.x;
    const int w = t >> 6;
    const int lane = t & 63;
    const int lrow = lane & 15;
    const int lk = (lane >> 4) * 8;
    const int row0 = blockIdx.x * 128;

    f32x4 acc[2][8] = {};

    for (int kt = 0; kt < 8; ++kt) {
#pragma unroll
        for (int i = 0; i < 4; ++i) {
            int flat = t + i * 256;
            int r = flat >> 3, c4 = flat & 7;
            int gr = row0 + r;
            float4 v = make_float4(0.f, 0.f, 0.f, 0.f);
            if (gr < N) v = *(const float4*)(x + (size_t)gr * 256 + kt * 32 + c4 * 4);
            ushort4 vh;
            vh.x = f2bf(v.x);
            vh.y = f2bf(v.y);
            vh.z = f2bf(v.z);
            vh.w = f2bf(v.w);
            *(ushort4*)(Ah + r * 40 + c4 * 4) = vh;
        }
#pragma unroll
        for (int i = 0; i < 2; ++i) {
            int flat = t + i * 256;
            int n = flat >> 2, c = flat & 3;
            *(short8*)(Bh + n * 40 + c * 8) =
                *(const short8*)(wt_hi + (size_t)n * 256 + kt * 32 + c * 8);
            *(short8*)(Bl + n * 40 + c * 8) =
                *(const short8*)(wt_lo + (size_t)n * 256 + kt * 32 + c * 8);
        }
        __syncthreads();

        short8 a0 = *(const short8*)(Ah + (w * 32 + lrow) * 40 + lk);
        short8 a1 = *(const short8*)(Ah + (w * 32 + 16 + lrow) * 40 + lk);
#pragma unroll
        for (int ni = 0; ni < 8; ++ni) {
            short8 bh = *(const short8*)(Bh + (ni * 16 + lrow) * 40 + lk);
            short8 bl = *(const short8*)(Bl + (ni * 16 + lrow) * 40 + lk);
            acc[0][ni] = __builtin_amdgcn_mfma_f32_16x16x32_bf16(a0, bh, acc[0][ni], 0, 0, 0);
            acc[1][ni] = __builtin_amdgcn_mfma_f32_16x16x32_bf16(a1, bh, acc[1][ni], 0, 0, 0);
            acc[0][ni] = __builtin_amdgcn_mfma_f32_16x16x32_bf16(a0, bl, acc[0][ni], 0, 0, 0);
            acc[1][ni] = __builtin_amdgcn_mfma_f32_16x16x32_bf16(a1, bl, acc[1][ni], 0, 0, 0);
        }
        __syncthreads();
    }

#pragma unroll
    for (int mi = 0; mi < 2; ++mi) {
        int rbase = row0 + w * 32 + mi * 16 + (lane >> 4) * 4;
#pragma unroll
        for (int r = 0; r < 4; ++r) {
            int gr = rbase + r;
            if (gr < N) {
                u16* p = xw1 + (size_t)gr * 128 + (lane & 15);
#pragma unroll
                for (int ni = 0; ni < 8; ++ni) p[ni * 16] = f2bf(acc[mi][ni][r]);
            }
        }
    }
}

// dinv from summed replicas; per-block count totals
__launch_bounds__(256)
__global__ void k_prep(const u64* __restrict__ hist,
                       float* __restrict__ dinv, int* __restrict__ blkTot, int N) {
    __shared__ int red[256];
    int t = threadIdx.x;
    int i = blockIdx.x * 256 + t;
    int cnt = 0;
    if (i < N) {
        u64 degfix = 0;
#pragma unroll
        for (int r = 0; r < 8; ++r) {
            u64 p = hist[(size_t)r * N + i];
            cnt += (int)(p >> 32);
            degfix += (p & 0xffffffffULL);
        }
        dinv[i] = rsqrtf((float)degfix * (1.0f / FIXSCALE) + 1.0f);
    }
    red[t] = cnt;
    __syncthreads();
#pragma unroll
    for (int off = 128; off > 0; off >>= 1) {
        if (t < off) red[t] += red[t + off];
        __syncthreads();
    }
    if (t == 0) blkTot[blockIdx.x] = red[0];
}

__launch_bounds__(512)
__global__ void k_scanblk(const int* __restrict__ blkTot, int* __restrict__ blkOff,
                          int* __restrict__ rowp, int NB, int N, int E) {
    __shared__ int s[512];
    int t = threadIdx.x;
    int v = (t < NB) ? blkTot[t] : 0;
    s[t] = v;
    __syncthreads();
    for (int off = 1; off < 512; off <<= 1) {
        int u = (t >= off) ? s[t - off] : 0;
        __syncthreads();
        s[t] += u;
        __syncthreads();
    }
    if (t < NB) blkOff[t] = s[t] - v;
    if (t == 0) rowp[N] = E;
}

// rowp + per-(node,replica) absolute base offsets
__launch_bounds__(256)
__global__ void k_rowp(const u64* __restrict__ hist, const int* __restrict__ blkOff,
                       int* __restrict__ rowp, int* __restrict__ base, int N) {
    __shared__ int s[256];
    int t = threadIdx.x;
    int i = blockIdx.x * 256 + t;
    int c[8];
    int cnt = 0;
    if (i < N) {
#pragma unroll
        for (int r = 0; r < 8; ++r) {
            c[r] = (int)(hist[(size_t)r * N + i] >> 32);
            cnt += c[r];
        }
    }
    s[t] = cnt;
    __syncthreads();
    for (int off = 1; off < 256; off <<= 1) {
        int u = (t >= off) ? s[t - off] : 0;
        __syncthreads();
        s[t] += u;
        __syncthreads();
    }
    if (i < N) {
        int run = blkOff[blockIdx.x] + s[t] - cnt;
        rowp[i] = run;
#pragma unroll
        for (int r = 0; r < 8; ++r) {
            base[(size_t)i * 8 + r] = run;
            run += c[r];
        }
    }
}

__global__ void k_fill(const int* __restrict__ src, const int* __restrict__ dst,
                       const float* __restrict__ ew, const int* __restrict__ rank,
                       const float* __restrict__ dinv, const int* __restrict__ base,
                       int2* __restrict__ entries, int E) {
    int e = blockIdx.x * 256 + threadIdx.x;
    if (e < E) {
        int s = src[e], d = dst[e];
        float w = dinv[s] * ew[e] * dinv[d];
        int rk = rank[e];
        int slot = base[(size_t)d * 8 + (rk >> 16)] + (rk & 0xffff);
        entries[slot] = make_int2(s, __float_as_int(w));
    }
}

// W1[256,128] f32 -> Wt_hi/Wt_lo[128,256] bf16 (transposed, split precision)
__global__ void k_wsplit(const float* __restrict__ W1, u16* __restrict__ wt_hi,
                         u16* __restrict__ wt_lo) {
    int idx = blockIdx.x * 256 + threadIdx.x;
    if (idx < 256 * 128) {
        int n = idx & 127, k = idx >> 7;
        float f = W1[idx];
        u16 h = f2bf(f);
        wt_hi[n * 256 + k] = h;
        wt_lo[n * 256 + k] = f2bf(f - bf2f(h));
    }
}

// gather layer 1: agg1[n] = dinv^2[n]*xw1[n] + sum_e w_e * xw1[src_e]
__launch_bounds__(256)
__global__ void k_gather1(const u16* __restrict__ xw1, const int2* __restrict__ entries,
                          const int* __restrict__ row, const float* __restrict__ dinv,
                          float* __restrict__ agg1, int N) {
    int g = (blockIdx.x * 256 + threadIdx.x) >> 5;
    if (g >= N) return;
    int j = (threadIdx.x & 31) * 4;
    float di = dinv[g];
    float d2 = di * di;
    ushort4 sv = *(const ushort4*)(xw1 + (size_t)g * 128 + j);
    float4 acc = make_float4(d2 * bf2f(sv.x), d2 * bf2f(sv.y),
                             d2 * bf2f(sv.z), d2 * bf2f(sv.w));
    int e = row[g], end = row[g + 1];
    for (; e + 2 <= end; e += 2) {
        int2 e0 = entries[e];
        int2 e1 = entries[e + 1];
        ushort4 v0 = *(const ushort4*)(xw1 + (size_t)e0.x * 128 + j);
        ushort4 v1 = *(const ushort4*)(xw1 + (size_t)e1.x * 128 + j);
        float w0 = __int_as_float(e0.y), w1 = __int_as_float(e1.y);
        acc.x += w0 * bf2f(v0.x) + w1 * bf2f(v1.x);
        acc.y += w0 * bf2f(v0.y) + w1 * bf2f(v1.y);
        acc.z += w0 * bf2f(v0.z) + w1 * bf2f(v1.z);
        acc.w += w0 * bf2f(v0.w) + w1 * bf2f(v1.w);
    }
    if (e < end) {
        int2 e0 = entries[e];
        ushort4 v0 = *(const ushort4*)(xw1 + (size_t)e0.x * 128 + j);
        float w0 = __int_as_float(e0.y);
        acc.x += w0 * bf2f(v0.x);
        acc.y += w0 * bf2f(v0.y);
        acc.z += w0 * bf2f(v0.z);
        acc.w += w0 * bf2f(v0.w);
    }
    *(float4*)(agg1 + (size_t)g * 128 + j) = acc;
}

// GEMM2: h = relu(agg1 + b1); hw2[N,48](bf16) = h @ W2[128,40], cols 40-47 = 0
__launch_bounds__(320)
__global__ void k_gemm2(const float* __restrict__ agg1, const float* __restrict__ W2,
                        const float* __restrict__ b1, u16* __restrict__ hw2, int N) {
    __shared__ float As[64 * 132];
    __shared__ float Bs[128 * 40];
    const int t = threadIdx.x;
    const int row0 = blockIdx.x * 64;

    for (int flat = t; flat < 128 * 40; flat += 320) Bs[flat] = W2[flat];

#pragma unroll
    for (int i = 0; i < 7; ++i) {
        int flat = t + i * 320;
        if (flat < 2048) {
            int r = flat >> 5, c4 = flat & 31;
            int gr = row0 + r;
            float4 v = make_float4(0.f, 0.f, 0.f, 0.f);
            if (gr < N) {
                v = *(const float4*)(agg1 + (size_t)gr * 128 + c4 * 4);
                float4 bb = *(const float4*)(b1 + c4 * 4);
                v.x = fmaxf(v.x + bb.x, 0.f);
                v.y = fmaxf(v.y + bb.y, 0.f);
                v.z = fmaxf(v.z + bb.z, 0.f);
                v.w = fmaxf(v.w + bb.w, 0.f);
            }
            *(float4*)(As + r * 132 + c4 * 4) = v;
        }
    }
    __syncthreads();

    const int tx = t % 40;
    const int ty = t / 40;
    float acc[8];
#pragma unroll
    for (int r = 0; r < 8; ++r) acc[r] = 0.f;
    for (int k = 0; k < 128; ++k) {
        float b = Bs[k * 40 + tx];
#pragma unroll
        for (int r = 0; r < 8; ++r) acc[r] += As[(ty * 8 + r) * 132 + k] * b;
    }
#pragma unroll
    for (int r = 0; r < 8; ++r) {
        int gr = row0 + ty * 8 + r;
        if (gr < N) hw2[(size_t)gr * HW2S + tx] = f2bf(acc[r]);
    }
    for (int idx = t; idx < 64 * 8; idx += 320) {
        int r = idx >> 3, c = 40 + (idx & 7);
        int gr = row0 + r;
        if (gr < N) hw2[(size_t)gr * HW2S + c] = 0;
    }
}

// gather layer 2 + bias + fused L2 normalize -> out
__launch_bounds__(256)
__global__ void k_gather2(const u16* __restrict__ hw2, const int2* __restrict__ entries,
                          const int* __restrict__ row, const float* __restrict__ dinv,
                          const float* __restrict__ b2, float* __restrict__ out, int N) {
    int g = (blockIdx.x * 256 + threadIdx.x) >> 3;
    if (g >= N) return;
    int l = threadIdx.x & 7;
    int c0 = l * 6;
    float di = dinv[g];
    float d2 = di * di;
    float bb[6];
#pragma unroll
    for (int k = 0; k < 6; ++k) bb[k] = (c0 + k < 40) ? b2[c0 + k] : 0.f;

    float acc[6];
    {
        const u16* hn = hw2 + (size_t)g * HW2S + c0;
        ushort2 s0 = *(const ushort2*)(hn);
        ushort2 s1 = *(const ushort2*)(hn + 2);
        ushort2 s2 = *(const ushort2*)(hn + 4);
        acc[0] = d2 * bf2f(s0.x) + bb[0];
        acc[1] = d2 * bf2f(s0.y) + bb[1];
        acc[2] = d2 * bf2f(s1.x) + bb[2];
        acc[3] = d2 * bf2f(s1.y) + bb[3];
        acc[4] = d2 * bf2f(s2.x) + bb[4];
        acc[5] = d2 * bf2f(s2.y) + bb[5];
    }
    int e = row[g], end = row[g + 1];
    for (; e < end; ++e) {
        int2 ent = entries[e];
        float w = __int_as_float(ent.y);
        const u16* hr = hw2 + (size_t)ent.x * HW2S + c0;
        ushort2 v0 = *(const ushort2*)(hr);
        ushort2 v1 = *(const ushort2*)(hr + 2);
        ushort2 v2 = *(const ushort2*)(hr + 4);
        acc[0] += w * bf2f(v0.x);
        acc[1] += w * bf2f(v0.y);
        acc[2] += w * bf2f(v1.x);
        acc[3] += w * bf2f(v1.y);
        acc[4] += w * bf2f(v2.x);
        acc[5] += w * bf2f(v2.y);
    }
    float ss = 0.f;
#pragma unroll
    for (int k = 0; k < 6; ++k) ss += acc[k] * acc[k];
    ss += __shfl_xor(ss, 1);
    ss += __shfl_xor(ss, 2);
    ss += __shfl_xor(ss, 4);
    float inv = 1.f / fmaxf(sqrtf(ss), 1e-12f);
#pragma unroll
    for (int k = 0; k < 6; ++k) {
        int c = c0 + k;
        if (c < 40) out[(size_t)g * 40 + c] = acc[k] * inv;
    }
}

extern "C" void kernel_launch(void* const* d_in, const int* in_sizes, int n_in,
                              void* d_out, int out_size, void* d_ws, size_t ws_size,
                              hipStream_t stream) {
    const float* x   = (const float*)d_in[0];
    const int*   ei  = (const int*)d_in[1];
    const float* ew  = (const float*)d_in[2];
    const float* W1  = (const float*)d_in[3];
    const float* b1  = (const float*)d_in[4];
    const float* W2  = (const float*)d_in[5];
    const float* b2  = (const float*)d_in[6];
    float* out = (float*)d_out;

    const int N = in_sizes[0] / 256;   // 100000
    const int E = in_sizes[2];         // 1600000
    const int* src = ei;
    const int* dst = ei + E;
    const int NB = (N + 255) / 256;

    char* ws = (char*)d_ws;
    size_t off = 0;
    auto take = [&](size_t bytes) -> void* {
        void* p = (void*)(ws + off);
        off += (bytes + 255) & ~(size_t)255;
        return p;
    };
    u64*   hist    = (u64*)take((size_t)8 * N * 8);        // 8 XCD-local replicas
    int*   rank    = (int*)take((size_t)E * 4);
    float* dinv    = (float*)take((size_t)N * 4);
    int*   blkTot  = (int*)take((size_t)NB * 4);
    int*   blkOff  = (int*)take((size_t)NB * 4);
    int*   rowp    = (int*)take((size_t)(N + 1) * 4);
    int*   base    = (int*)take((size_t)N * 8 * 4);        // per (node, replica)
    int2*  entries = (int2*)take((size_t)E * 8);
    u16*   wt_hi   = (u16*)take((size_t)128 * 256 * 2);
    u16*   wt_lo   = (u16*)take((size_t)128 * 256 * 2);
    u16*   xw1     = (u16*)take((size_t)N * 128 * 2);
    float* agg1    = (float*)take((size_t)N * 128 * 4);
    u16*   hw2     = (u16*)take((size_t)N * HW2S * 2);

    hipMemsetAsync(hist, 0, (size_t)8 * N * 8, stream);
    k_wsplit<<<(256 * 128 + 255) / 256, 256, 0, stream>>>(W1, wt_hi, wt_lo);

    const int gB = (N + 127) / 128;           // 782 gemm tiles
    const int dB = (E + 255) / 256;           // 6250 deg chunks
    k_fat1<<<gB + dB, 256, 0, stream>>>(x, wt_hi, wt_lo, xw1, N,
                                        dst, ew, hist, rank, E, gB);

    k_prep<<<NB, 256, 0, stream>>>(hist, dinv, blkTot, N);
    k_scanblk<<<1, 512, 0, stream>>>(blkTot, blkOff, rowp, NB, N, E);
    k_rowp<<<NB, 256, 0, stream>>>(hist, blkOff, rowp, base, N);
    k_fill<<<(E + 255) / 256, 256, 0, stream>>>(src, dst, ew, rank, dinv, base, entries, E);

    k_gather1<<<(N * 32 + 255) / 256, 256, 0, stream>>>(xw1, entries, rowp, dinv, agg1, N);
    k_gemm2<<<(N + 63) / 64, 320, 0, stream>>>(agg1, W2, b1, hw2, N);
    k_gather2<<<(N * 8 + 255) / 256, 256, 0, stream>>>(hw2, entries, rowp, dinv, b2, out, N);
}

// Round 11
// 294.214 us; speedup vs baseline: 1.1598x; 1.1035x over previous
//
#include <hip/hip_runtime.h>

// ---------------------------------------------------------------------------
// 2-layer GCN forward (PyG GCNConv, add_self_loops, sym-norm), CSR-gather.
//   dinv = rsqrt(segsum(ew,dst)+1)
//   h    = relu( Agg(norm, x@W1) + dinv^2*(x@W1) + b1 )
//   out  = L2norm( Agg(norm, h@W2) + dinv^2*(h@W2) + b2 )
// CSR build = LDS counting sort (NO global atomics — the 74us atomic cap
// measured in R6-R9 is an L2/fabric atomic-throughput limit, unfixable by
// scheduling). entries store (src, ew*dinv_dst); gathers apply dinv[src].
// GEMM1: bf16 MFMA; W1 hi+lo split, x single bf16. xw1 bf16. hw2 bf16 pad-48.
// ---------------------------------------------------------------------------

typedef unsigned short u16;
typedef __attribute__((ext_vector_type(8))) short short8;
typedef __attribute__((ext_vector_type(4))) float f32x4;

#define FIXSCALE 4194304.0f   // 2^22 fixed-point for deterministic deg
#define HW2S 48               // hw2 row stride (bf16), 40 real + 8 pad
#define NSLAB 640             // sort slabs (pass 1/3 blocks)
#define MAXBUCK 832           // LDS capacity for bucket counters (>= NBUCK)

static __device__ inline u16 f2bf(float f) {            // RNE f32 -> bf16 bits
    unsigned u = __float_as_uint(f);
    return (u16)((u + 0x7fffu + ((u >> 16) & 1u)) >> 16);
}
static __device__ inline float bf2f(u16 h) { return __uint_as_float(((unsigned)h) << 16); }

// ---- FAT kernel: [0,gB) gemm1 tiles; [gB,gB+NSLAB) sort-pass-1 counting ----
__launch_bounds__(256)
__global__ void k_fat1(const float* __restrict__ x, const u16* __restrict__ wt_hi,
                       const u16* __restrict__ wt_lo, u16* __restrict__ xw1, int N,
                       const int* __restrict__ dst, int* __restrict__ cnt1,
                       int E, int gB, int EPB, int NBUCK) {
    __shared__ __align__(16) u16 Ah[128 * 40];
    __shared__ __align__(16) u16 Bh[128 * 40];
    __shared__ __align__(16) u16 Bl[128 * 40];

    if (blockIdx.x >= gB) {
        // ---- pass 1: per-slab bucket histogram (LDS atomics only) ----
        int b = blockIdx.x - gB;
        int* cnt = (int*)Ah;
        for (int j = threadIdx.x; j < NBUCK; j += 256) cnt[j] = 0;
        __syncthreads();
        int beg = b * EPB, end = min(beg + EPB, E);
        for (int i = beg + threadIdx.x; i < end; i += 256)
            atomicAdd(&cnt[dst[i] >> 7], 1);
        __syncthreads();
        for (int j = threadIdx.x; j < NBUCK; j += 256)
            cnt1[(size_t)b * NBUCK + j] = cnt[j];
        return;
    }

    // ---------------- gemm1 part (MFMA) ----------------
    const int t = threadIdx.x;
    const int w = t >> 6;
    const int lane = t & 63;
    const int lrow = lane & 15;
    const int lk = (lane >> 4) * 8;
    const int row0 = blockIdx.x * 128;

    f32x4 acc[2][8] = {};

    for (int kt = 0; kt < 8; ++kt) {
#pragma unroll
        for (int i = 0; i < 4; ++i) {
            int flat = t + i * 256;
            int r = flat >> 3, c4 = flat & 7;
            int gr = row0 + r;
            float4 v = make_float4(0.f, 0.f, 0.f, 0.f);
            if (gr < N) v = *(const float4*)(x + (size_t)gr * 256 + kt * 32 + c4 * 4);
            ushort4 vh;
            vh.x = f2bf(v.x);
            vh.y = f2bf(v.y);
            vh.z = f2bf(v.z);
            vh.w = f2bf(v.w);
            *(ushort4*)(Ah + r * 40 + c4 * 4) = vh;
        }
#pragma unroll
        for (int i = 0; i < 2; ++i) {
            int flat = t + i * 256;
            int n = flat >> 2, c = flat & 3;
            *(short8*)(Bh + n * 40 + c * 8) =
                *(const short8*)(wt_hi + (size_t)n * 256 + kt * 32 + c * 8);
            *(short8*)(Bl + n * 40 + c * 8) =
                *(const short8*)(wt_lo + (size_t)n * 256 + kt * 32 + c * 8);
        }
        __syncthreads();

        short8 a0 = *(const short8*)(Ah + (w * 32 + lrow) * 40 + lk);
        short8 a1 = *(const short8*)(Ah + (w * 32 + 16 + lrow) * 40 + lk);
#pragma unroll
        for (int ni = 0; ni < 8; ++ni) {
            short8 bh = *(const short8*)(Bh + (ni * 16 + lrow) * 40 + lk);
            short8 bl = *(const short8*)(Bl + (ni * 16 + lrow) * 40 + lk);
            acc[0][ni] = __builtin_amdgcn_mfma_f32_16x16x32_bf16(a0, bh, acc[0][ni], 0, 0, 0);
            acc[1][ni] = __builtin_amdgcn_mfma_f32_16x16x32_bf16(a1, bh, acc[1][ni], 0, 0, 0);
            acc[0][ni] = __builtin_amdgcn_mfma_f32_16x16x32_bf16(a0, bl, acc[0][ni], 0, 0, 0);
            acc[1][ni] = __builtin_amdgcn_mfma_f32_16x16x32_bf16(a1, bl, acc[1][ni], 0, 0, 0);
        }
        __syncthreads();
    }

#pragma unroll
    for (int mi = 0; mi < 2; ++mi) {
        int rbase = row0 + w * 32 + mi * 16 + (lane >> 4) * 4;
#pragma unroll
        for (int r = 0; r < 4; ++r) {
            int gr = rbase + r;
            if (gr < N) {
                u16* p = xw1 + (size_t)gr * 128 + (lane & 15);
#pragma unroll
                for (int ni = 0; ni < 8; ++ni) p[ni * 16] = f2bf(acc[mi][ni][r]);
            }
        }
    }
}

// pass 2a: per bucket, exclusive scan over the NSLAB slab counts (in place)
__launch_bounds__(NSLAB)
__global__ void k_s2a(int* __restrict__ cnt1, int* __restrict__ colTot, int NBUCK) {
    __shared__ int s[NSLAB];
    int j = blockIdx.x;
    int t = threadIdx.x;
    int v = cnt1[(size_t)t * NBUCK + j];
    s[t] = v;
    __syncthreads();
    for (int off = 1; off < NSLAB; off <<= 1) {
        int u = (t >= off) ? s[t - off] : 0;
        __syncthreads();
        s[t] += u;
        __syncthreads();
    }
    cnt1[(size_t)t * NBUCK + j] = s[t] - v;   // exclusive within bucket
    if (t == NSLAB - 1) colTot[j] = s[t];
}

// pass 2b: scan bucket totals -> bucketBase; rowp[N]=E
__launch_bounds__(1024)
__global__ void k_s2b(const int* __restrict__ colTot, int* __restrict__ bucketBase,
                      int* __restrict__ rowp, int NBUCK, int N, int E) {
    __shared__ int s[1024];
    int t = threadIdx.x;
    int v = (t < NBUCK) ? colTot[t] : 0;
    s[t] = v;
    __syncthreads();
    for (int off = 1; off < 1024; off <<= 1) {
        int u = (t >= off) ? s[t - off] : 0;
        __syncthreads();
        s[t] += u;
        __syncthreads();
    }
    if (t < NBUCK) bucketBase[t] = s[t] - v;
    if (t == NBUCK - 1) bucketBase[NBUCK] = s[t];
    if (t == 0) rowp[N] = E;
}

// pass 3: scatter (src, ew, dst) records to bucket-major tmp (LDS cursors)
__launch_bounds__(256)
__global__ void k_s3(const int* __restrict__ src, const int* __restrict__ dst,
                     const float* __restrict__ ew, const int* __restrict__ cnt1,
                     const int* __restrict__ bucketBase, int4* __restrict__ tmp,
                     int E, int EPB, int NBUCK) {
    __shared__ int ldsOff[MAXBUCK];
    int b = blockIdx.x, t = threadIdx.x;
    for (int j = t; j < NBUCK; j += 256)
        ldsOff[j] = bucketBase[j] + cnt1[(size_t)b * NBUCK + j];
    __syncthreads();
    int beg = b * EPB, end = min(beg + EPB, E);
    for (int i = beg + t; i < end; i += 256) {
        int d = dst[i];
        int slot = atomicAdd(&ldsOff[d >> 7], 1);
        tmp[slot] = make_int4(src[i], __float_as_int(ew[i]), d, 0);
    }
}

// pass 4: per bucket (128 nodes): counts+deg (LDS), scan -> rowp/dinv,
// then write entries (src, ew*dinv_dst) to final contiguous slots.
__launch_bounds__(256)
__global__ void k_s4(const int4* __restrict__ tmp, const int* __restrict__ bucketBase,
                     int* __restrict__ rowp, float* __restrict__ dinv,
                     int2* __restrict__ entries, int N) {
    __shared__ int cnt[128];
    __shared__ unsigned degfix[128];
    __shared__ int sc[128];
    __shared__ int nextOff[128];
    __shared__ float dl[128];
    int k = blockIdx.x, t = threadIdx.x;
    int base = bucketBase[k], endb = bucketBase[k + 1];
    if (t < 128) { cnt[t] = 0; degfix[t] = 0; }
    __syncthreads();
    for (int i = base + t; i < endb; i += 256) {
        int4 r = tmp[i];
        int lid = r.z & 127;
        atomicAdd(&cnt[lid], 1);
        atomicAdd(&degfix[lid],
                  (unsigned)__float2uint_rn(__int_as_float(r.y) * FIXSCALE));
    }
    __syncthreads();
    if (t < 128) sc[t] = cnt[t];
    __syncthreads();
    for (int off = 1; off < 128; off <<= 1) {
        int u = 0;
        if (t < 128 && t >= off) u = sc[t - off];
        __syncthreads();
        if (t < 128) sc[t] += u;
        __syncthreads();
    }
    if (t < 128) {
        int off0 = base + sc[t] - cnt[t];
        nextOff[t] = off0;
        float di = rsqrtf((float)degfix[t] * (1.0f / FIXSCALE) + 1.0f);
        dl[t] = di;
        int gn = k * 128 + t;
        if (gn < N) { rowp[gn] = off0; dinv[gn] = di; }
    }
    __syncthreads();
    for (int i = base + t; i < endb; i += 256) {
        int4 r = tmp[i];
        int lid = r.z & 127;
        int slot = atomicAdd(&nextOff[lid], 1);
        float w = __int_as_float(r.y) * dl[lid];       // ew * dinv[dst]
        entries[slot] = make_int2(r.x, __float_as_int(w));
    }
}

// W1[256,128] f32 -> Wt_hi/Wt_lo[128,256] bf16 (transposed, split precision)
__global__ void k_wsplit(const float* __restrict__ W1, u16* __restrict__ wt_hi,
                         u16* __restrict__ wt_lo) {
    int idx = blockIdx.x * 256 + threadIdx.x;
    if (idx < 256 * 128) {
        int n = idx & 127, k = idx >> 7;
        float f = W1[idx];
        u16 h = f2bf(f);
        wt_hi[n * 256 + k] = h;
        wt_lo[n * 256 + k] = f2bf(f - bf2f(h));
    }
}

// gather layer 1: agg1[n] = dinv^2[n]*xw1[n] + sum_e (w_e*dinv[src_e])*xw1[src_e]
__launch_bounds__(256)
__global__ void k_gather1(const u16* __restrict__ xw1, const int2* __restrict__ entries,
                          const int* __restrict__ row, const float* __restrict__ dinv,
                          float* __restrict__ agg1, int N) {
    int g = (blockIdx.x * 256 + threadIdx.x) >> 5;
    if (g >= N) return;
    int j = (threadIdx.x & 31) * 4;
    float di = dinv[g];
    float d2 = di * di;
    ushort4 sv = *(const ushort4*)(xw1 + (size_t)g * 128 + j);
    float4 acc = make_float4(d2 * bf2f(sv.x), d2 * bf2f(sv.y),
                             d2 * bf2f(sv.z), d2 * bf2f(sv.w));
    int e = row[g], end = row[g + 1];
    for (; e + 2 <= end; e += 2) {
        int2 e0 = entries[e];
        int2 e1 = entries[e + 1];
        ushort4 v0 = *(const ushort4*)(xw1 + (size_t)e0.x * 128 + j);
        ushort4 v1 = *(const ushort4*)(xw1 + (size_t)e1.x * 128 + j);
        float w0 = __int_as_float(e0.y) * dinv[e0.x];
        float w1 = __int_as_float(e1.y) * dinv[e1.x];
        acc.x += w0 * bf2f(v0.x) + w1 * bf2f(v1.x);
        acc.y += w0 * bf2f(v0.y) + w1 * bf2f(v1.y);
        acc.z += w0 * bf2f(v0.z) + w1 * bf2f(v1.z);
        acc.w += w0 * bf2f(v0.w) + w1 * bf2f(v1.w);
    }
    if (e < end) {
        int2 e0 = entries[e];
        ushort4 v0 = *(const ushort4*)(xw1 + (size_t)e0.x * 128 + j);
        float w0 = __int_as_float(e0.y) * dinv[e0.x];
        acc.x += w0 * bf2f(v0.x);
        acc.y += w0 * bf2f(v0.y);
        acc.z += w0 * bf2f(v0.z);
        acc.w += w0 * bf2f(v0.w);
    }
    *(float4*)(agg1 + (size_t)g * 128 + j) = acc;
}

// GEMM2: h = relu(agg1 + b1); hw2[N,48](bf16) = h @ W2[128,40], cols 40-47 = 0
__launch_bounds__(320)
__global__ void k_gemm2(const float* __restrict__ agg1, const float* __restrict__ W2,
                        const float* __restrict__ b1, u16* __restrict__ hw2, int N) {
    __shared__ float As[64 * 132];
    __shared__ float Bs[128 * 40];
    const int t = threadIdx.x;
    const int row0 = blockIdx.x * 64;

    for (int flat = t; flat < 128 * 40; flat += 320) Bs[flat] = W2[flat];

#pragma unroll
    for (int i = 0; i < 7; ++i) {
        int flat = t + i * 320;
        if (flat < 2048) {
            int r = flat >> 5, c4 = flat & 31;
            int gr = row0 + r;
            float4 v = make_float4(0.f, 0.f, 0.f, 0.f);
            if (gr < N) {
                v = *(const float4*)(agg1 + (size_t)gr * 128 + c4 * 4);
                float4 bb = *(const float4*)(b1 + c4 * 4);
                v.x = fmaxf(v.x + bb.x, 0.f);
                v.y = fmaxf(v.y + bb.y, 0.f);
                v.z = fmaxf(v.z + bb.z, 0.f);
                v.w = fmaxf(v.w + bb.w, 0.f);
            }
            *(float4*)(As + r * 132 + c4 * 4) = v;
        }
    }
    __syncthreads();

    const int tx = t % 40;
    const int ty = t / 40;
    float acc[8];
#pragma unroll
    for (int r = 0; r < 8; ++r) acc[r] = 0.f;
    for (int k = 0; k < 128; ++k) {
        float b = Bs[k * 40 + tx];
#pragma unroll
        for (int r = 0; r < 8; ++r) acc[r] += As[(ty * 8 + r) * 132 + k] * b;
    }
#pragma unroll
    for (int r = 0; r < 8; ++r) {
        int gr = row0 + ty * 8 + r;
        if (gr < N) hw2[(size_t)gr * HW2S + tx] = f2bf(acc[r]);
    }
    for (int idx = t; idx < 64 * 8; idx += 320) {
        int r = idx >> 3, c = 40 + (idx & 7);
        int gr = row0 + r;
        if (gr < N) hw2[(size_t)gr * HW2S + c] = 0;
    }
}

// gather layer 2 + bias + fused L2 normalize -> out
__launch_bounds__(256)
__global__ void k_gather2(const u16* __restrict__ hw2, const int2* __restrict__ entries,
                          const int* __restrict__ row, const float* __restrict__ dinv,
                          const float* __restrict__ b2, float* __restrict__ out, int N) {
    int g = (blockIdx.x * 256 + threadIdx.x) >> 3;
    if (g >= N) return;
    int l = threadIdx.x & 7;
    int c0 = l * 6;
    float di = dinv[g];
    float d2 = di * di;
    float bb[6];
#pragma unroll
    for (int k = 0; k < 6; ++k) bb[k] = (c0 + k < 40) ? b2[c0 + k] : 0.f;

    float acc[6];
    {
        const u16* hn = hw2 + (size_t)g * HW2S + c0;
        ushort2 s0 = *(const ushort2*)(hn);
        ushort2 s1 = *(const ushort2*)(hn + 2);
        ushort2 s2 = *(const ushort2*)(hn + 4);
        acc[0] = d2 * bf2f(s0.x) + bb[0];
        acc[1] = d2 * bf2f(s0.y) + bb[1];
        acc[2] = d2 * bf2f(s1.x) + bb[2];
        acc[3] = d2 * bf2f(s1.y) + bb[3];
        acc[4] = d2 * bf2f(s2.x) + bb[4];
        acc[5] = d2 * bf2f(s2.y) + bb[5];
    }
    int e = row[g], end = row[g + 1];
    for (; e < end; ++e) {
        int2 ent = entries[e];
        float w = __int_as_float(ent.y) * dinv[ent.x];
        const u16* hr = hw2 + (size_t)ent.x * HW2S + c0;
        ushort2 v0 = *(const ushort2*)(hr);
        ushort2 v1 = *(const ushort2*)(hr + 2);
        ushort2 v2 = *(const ushort2*)(hr + 4);
        acc[0] += w * bf2f(v0.x);
        acc[1] += w * bf2f(v0.y);
        acc[2] += w * bf2f(v1.x);
        acc[3] += w * bf2f(v1.y);
        acc[4] += w * bf2f(v2.x);
        acc[5] += w * bf2f(v2.y);
    }
    float ss = 0.f;
#pragma unroll
    for (int k = 0; k < 6; ++k) ss += acc[k] * acc[k];
    ss += __shfl_xor(ss, 1);
    ss += __shfl_xor(ss, 2);
    ss += __shfl_xor(ss, 4);
    float inv = 1.f / fmaxf(sqrtf(ss), 1e-12f);
#pragma unroll
    for (int k = 0; k < 6; ++k) {
        int c = c0 + k;
        if (c < 40) out[(size_t)g * 40 + c] = acc[k] * inv;
    }
}

extern "C" void kernel_launch(void* const* d_in, const int* in_sizes, int n_in,
                              void* d_out, int out_size, void* d_ws, size_t ws_size,
                              hipStream_t stream) {
    const float* x   = (const float*)d_in[0];
    const int*   ei  = (const int*)d_in[1];
    const float* ew  = (const float*)d_in[2];
    const float* W1  = (const float*)d_in[3];
    const float* b1  = (const float*)d_in[4];
    const float* W2  = (const float*)d_in[5];
    const float* b2  = (const float*)d_in[6];
    float* out = (float*)d_out;

    const int N = in_sizes[0] / 256;   // 100000
    const int E = in_sizes[2];         // 1600000
    const int* src = ei;
    const int* dst = ei + E;
    const int NBUCK = (N + 127) >> 7;  // 782
    const int EPB = (E + NSLAB - 1) / NSLAB;

    char* ws = (char*)d_ws;
    size_t off = 0;
    auto take = [&](size_t bytes) -> void* {
        void* p = (void*)(ws + off);
        off += (bytes + 255) & ~(size_t)255;
        return p;
    };
    int*   cnt1    = (int*)take((size_t)NSLAB * NBUCK * 4);   // 2MB
    int*   colTot  = (int*)take((size_t)NBUCK * 4);
    int*   bucketBase = (int*)take((size_t)(NBUCK + 1) * 4);
    int*   rowp    = (int*)take((size_t)(N + 1) * 4);
    float* dinv    = (float*)take((size_t)N * 4);
    int4*  tmp     = (int4*)take((size_t)E * 16);             // 25.6MB
    int2*  entries = (int2*)take((size_t)E * 8);              // 12.8MB
    u16*   wt_hi   = (u16*)take((size_t)128 * 256 * 2);
    u16*   wt_lo   = (u16*)take((size_t)128 * 256 * 2);
    u16*   xw1     = (u16*)take((size_t)N * 128 * 2);
    float* agg1    = (float*)take((size_t)N * 128 * 4);
    u16*   hw2     = (u16*)take((size_t)N * HW2S * 2);

    k_wsplit<<<(256 * 128 + 255) / 256, 256, 0, stream>>>(W1, wt_hi, wt_lo);

    const int gB = (N + 127) / 128;           // 782 gemm tiles
    k_fat1<<<gB + NSLAB, 256, 0, stream>>>(x, wt_hi, wt_lo, xw1, N,
                                           dst, cnt1, E, gB, EPB, NBUCK);

    k_s2a<<<NBUCK, NSLAB, 0, stream>>>(cnt1, colTot, NBUCK);
    k_s2b<<<1, 1024, 0, stream>>>(colTot, bucketBase, rowp, NBUCK, N, E);
    k_s3<<<NSLAB, 256, 0, stream>>>(src, dst, ew, cnt1, bucketBase, tmp, E, EPB, NBUCK);
    k_s4<<<NBUCK, 256, 0, stream>>>(tmp, bucketBase, rowp, dinv, entries, N);

    k_gather1<<<(N * 32 + 255) / 256, 256, 0, stream>>>(xw1, entries, rowp, dinv, agg1, N);
    k_gemm2<<<(N + 63) / 64, 320, 0, stream>>>(agg1, W2, b1, hw2, N);
    k_gather2<<<(N * 8 + 255) / 256, 256, 0, stream>>>(hw2, entries, rowp, dinv, b2, out, N);
}